// Round 1
// baseline (6633.895 us; speedup 1.0000x reference)
//
#include <hip/hip_runtime.h>
#include <hip/hip_bf16.h>

#define TT 512
#define NB 1024

typedef float f32x4 __attribute__((ext_vector_type(4)));
typedef __bf16 bf16x8 __attribute__((ext_vector_type(8)));

// ---- workspace layout (units: __bf16 elements) ----
// Each 256x256 matrix packed as [kt][nt][lane][j] B-fragments for
// v_mfma_f32_16x16x32_bf16: B[k = kt*32 + (lane>>4)*8 + j][n = nt*16 + (lane&15)]
#define OFF_WHP   0
#define OFF_WMH   65536
#define OFF_WPOST 131072
#define OFF_WR1   196608
#define OFF_WMX   262144
#define OFF_WCP   327680   // 64x256 -> 16384 elems
#define WS_ELEMS  344064

__global__ __launch_bounds__(256) void pack_weights(
    const float* __restrict__ Whp, const float* __restrict__ Wm,
    const float* __restrict__ Wcp, const float* __restrict__ Whpost,
    const float* __restrict__ Wr1, __bf16* __restrict__ wsp) {
  int id = blockIdx.x * 256 + threadIdx.x;
  if (id >= WS_ELEMS) return;
  int rel; const float* src;
  if (id < OFF_WMH)        { rel = id - OFF_WHP;   src = Whp; }
  else if (id < OFF_WPOST) { rel = id - OFF_WMH;   src = Wm; }          // Wm rows 0..255
  else if (id < OFF_WR1)   { rel = id - OFF_WPOST; src = Whpost; }
  else if (id < OFF_WMX)   { rel = id - OFF_WR1;   src = Wr1; }
  else if (id < OFF_WCP)   { rel = id - OFF_WMX;   src = Wm + 256*256; } // Wm rows 256..511
  else                     { rel = id - OFF_WCP;   src = Wcp; }
  int j    = rel & 7;
  int lane = (rel >> 3) & 63;
  int nt   = (rel >> 9) & 15;
  int kt   = rel >> 13;
  int k = kt*32 + ((lane >> 4) << 3) + j;
  int n = nt*16 + (lane & 15);
  wsp[id] = (__bf16)src[k*256 + n];
}

__device__ __forceinline__ float tanh_fast(float x) {
  // tanh(x) = 1 - 2/(exp(2x)+1); robust at +-inf via native exp/rcp
  float t = __expf(2.0f * x);
  return 1.0f - __fdividef(2.0f, t + 1.0f);
}

// Streamed GEMM stage: acc[4] covers 16 rows x (wave's 4 ntiles of 16 cols).
// A-fragments come from an LDS tile stored in fragment order:
//   tile[(kt*64 + lane)*8 + j]  <->  A[m = lane&15][k = kt*32 + (lane>>4)*8 + j]
// B-fragments streamed from L2 with depth-4 register prefetch.
template<int KT>
__device__ __forceinline__ void gemm_stream(
    f32x4 acc[4], const __bf16* __restrict__ Wp,
    const __bf16* atile, int wv, int lane) {
  constexpr int PF = (KT < 4) ? KT : 4;
  bf16x8 bbuf[PF][4];
  #pragma unroll
  for (int p = 0; p < PF; ++p)
    #pragma unroll
    for (int a = 0; a < 4; ++a)
      bbuf[p][a] = *(const bf16x8*)(Wp + ((p*16 + wv*4 + a)*64 + lane)*8);
  #pragma unroll
  for (int kt = 0; kt < KT; ++kt) {
    bf16x8 af = *(const bf16x8*)(atile + (kt*64 + lane)*8);
    #pragma unroll
    for (int a = 0; a < 4; ++a)
      acc[a] = __builtin_amdgcn_mfma_f32_16x16x32_bf16(af, bbuf[kt % PF][a], acc[a], 0, 0, 0);
    if (kt + PF < KT) {
      #pragma unroll
      for (int a = 0; a < 4; ++a)
        bbuf[kt % PF][a] = *(const bf16x8*)(Wp + (((kt+PF)*16 + wv*4 + a)*64 + lane)*8);
    }
  }
}

// C-layout (col = lane&15 + strip, row = (lane>>4)*4 + r) -> tanh -> bf16 ->
// LDS tile in A-fragment order for the next GEMM.
__device__ __forceinline__ void tanh_store(__bf16* tile, const f32x4 acc[4],
                                           int wv, int lane) {
  int l15 = lane & 15, lq = lane >> 4;
  #pragma unroll
  for (int a = 0; a < 4; ++a) {
    int col = wv*64 + a*16 + l15;
    int kt  = col >> 5;
    int lp  = 16 * ((col & 31) >> 3);
    int j   = col & 7;
    #pragma unroll
    for (int r = 0; r < 4; ++r) {
      int row = lq*4 + r;
      tile[(kt*64 + lp + row)*8 + j] = (__bf16)tanh_fast(acc[a][r]);
    }
  }
}

__device__ __forceinline__ void init_acc(f32x4 acc[4], const float* b,
                                         int wv, int l15) {
  #pragma unroll
  for (int a = 0; a < 4; ++a) {
    float v = b[wv*64 + a*16 + l15];
    acc[a] = (f32x4){v, v, v, v};
  }
}

__global__ __launch_bounds__(256) void rnn_seq(
    const float* __restrict__ x, const __bf16* __restrict__ wsp,
    const float* __restrict__ bhp, const float* __restrict__ bcp,
    const float* __restrict__ bm, const float* __restrict__ bhpost,
    const float* __restrict__ br1, const float* __restrict__ Wr2,
    const float* __restrict__ br2, float* __restrict__ out) {
  // tiles: 0 = h (persistent), 1 = tanh(hp), 2 = tanh(cp), 3 = tanh(u)
  __shared__ __bf16 tiles[4][4096];
  __shared__ float  lb[6*256];   // bhp, bcp, bm, bhpost, br1, Wr2

  const int tid  = threadIdx.x;
  const int wv   = tid >> 6;
  const int lane = tid & 63;
  const int l15  = lane & 15, lq = lane >> 4;
  const int n0   = blockIdx.x * 16;

  lb[0*256 + tid] = bhp[tid];
  lb[1*256 + tid] = bcp[tid];
  lb[2*256 + tid] = bm[tid];
  lb[3*256 + tid] = bhpost[tid];
  lb[4*256 + tid] = br1[tid];
  lb[5*256 + tid] = Wr2[tid];
  for (int i = tid; i < 4096; i += 256) tiles[0][i] = (__bf16)0.0f;  // h0 = 0
  const float br2v = br2[0] * 0.25f;   // each of 4 waves contributes br2/4
  __syncthreads();

  for (int t = 0; t < TT; ++t) {
    // x A-fragments (K=64 -> 2 ktiles), fp32 -> bf16 in regs
    const float* xp = x + ((size_t)t*NB + n0 + l15)*64 + lq*8;
    f32x4 xa0 = *(const f32x4*)(xp);
    f32x4 xa1 = *(const f32x4*)(xp + 4);
    f32x4 xb0 = *(const f32x4*)(xp + 32);
    f32x4 xb1 = *(const f32x4*)(xp + 36);
    bf16x8 xf0, xf1;
    #pragma unroll
    for (int j = 0; j < 4; ++j) {
      xf0[j] = (__bf16)xa0[j]; xf0[4+j] = (__bf16)xa1[j];
      xf1[j] = (__bf16)xb0[j]; xf1[4+j] = (__bf16)xb1[j];
    }

    // ---- stage 1: hp = h@Whp + bhp ; cp = x@Wcp + bcp ----
    f32x4 ah[4], ac[4];
    init_acc(ah, lb + 0*256, wv, l15);
    init_acc(ac, lb + 1*256, wv, l15);
    {
      bf16x8 bb[2][4];
      #pragma unroll
      for (int p = 0; p < 2; ++p)
        #pragma unroll
        for (int a = 0; a < 4; ++a)
          bb[p][a] = *(const bf16x8*)(wsp + OFF_WCP + ((p*16 + wv*4 + a)*64 + lane)*8);
      #pragma unroll
      for (int a = 0; a < 4; ++a) {
        ac[a] = __builtin_amdgcn_mfma_f32_16x16x32_bf16(xf0, bb[0][a], ac[a], 0, 0, 0);
        ac[a] = __builtin_amdgcn_mfma_f32_16x16x32_bf16(xf1, bb[1][a], ac[a], 0, 0, 0);
      }
    }
    gemm_stream<8>(ah, wsp + OFF_WHP, tiles[0], wv, lane);
    tanh_store(tiles[1], ah, wv, lane);
    tanh_store(tiles[2], ac, wv, lane);
    __syncthreads();

    // ---- stage 2: u = tanh(hp)@Wm_h + tanh(cp)@Wm_x + bm ----
    f32x4 au[4];
    init_acc(au, lb + 2*256, wv, l15);
    gemm_stream<8>(au, wsp + OFF_WMH, tiles[1], wv, lane);
    gemm_stream<8>(au, wsp + OFF_WMX, tiles[2], wv, lane);
    tanh_store(tiles[3], au, wv, lane);
    __syncthreads();

    // ---- stage 3: h_new = tanh(tanh(u)@Whpost + bhpost) ----
    f32x4 ap[4];
    init_acc(ap, lb + 3*256, wv, l15);
    gemm_stream<8>(ap, wsp + OFF_WPOST, tiles[3], wv, lane);
    tanh_store(tiles[0], ap, wv, lane);
    __syncthreads();

    // ---- stage 4: out = relu(h@Wr1 + br1) @ Wr2 + br2 ----
    f32x4 ar[4];
    init_acc(ar, lb + 4*256, wv, l15);
    gemm_stream<8>(ar, wsp + OFF_WR1, tiles[0], wv, lane);
    float s[4] = {0.f, 0.f, 0.f, 0.f};
    #pragma unroll
    for (int a = 0; a < 4; ++a) {
      float w2 = lb[5*256 + wv*64 + a*16 + l15];
      #pragma unroll
      for (int r = 0; r < 4; ++r)
        s[r] += fmaxf(ar[a][r], 0.0f) * w2;
    }
    #pragma unroll
    for (int m = 1; m < 16; m <<= 1) {
      #pragma unroll
      for (int r = 0; r < 4; ++r) s[r] += __shfl_xor(s[r], m, 64);
    }
    if (l15 == 0) {
      #pragma unroll
      for (int r = 0; r < 4; ++r)
        atomicAdd(out + (size_t)t*NB + n0 + lq*4 + r, s[r] + br2v);
    }
  }
}

extern "C" void kernel_launch(void* const* d_in, const int* in_sizes, int n_in,
                              void* d_out, int out_size, void* d_ws, size_t ws_size,
                              hipStream_t stream) {
  const float* x      = (const float*)d_in[0];
  const float* Whp    = (const float*)d_in[1];
  const float* bhp    = (const float*)d_in[2];
  const float* Wcp    = (const float*)d_in[3];
  const float* bcp    = (const float*)d_in[4];
  const float* Wm     = (const float*)d_in[5];
  const float* bm     = (const float*)d_in[6];
  const float* Whpost = (const float*)d_in[7];
  const float* bhpost = (const float*)d_in[8];
  const float* Wr1    = (const float*)d_in[9];
  const float* br1    = (const float*)d_in[10];
  const float* Wr2    = (const float*)d_in[11];
  const float* br2    = (const float*)d_in[12];
  __bf16* wsp = (__bf16*)d_ws;
  float*  out = (float*)d_out;

  if (ws_size < (size_t)WS_ELEMS * sizeof(__bf16)) return;  // need ~688 KB scratch

  hipMemsetAsync(out, 0, (size_t)out_size * sizeof(float), stream);
  pack_weights<<<WS_ELEMS / 256, 256, 0, stream>>>(Whp, Wm, Wcp, Whpost, Wr1, wsp);
  rnn_seq<<<64, 256, 0, stream>>>(x, wsp, bhp, bcp, bm, bhpost, br1, Wr2, br2, out);
}

// Round 2
// 6203.601 us; speedup vs baseline: 1.0694x; 1.0694x over previous
//
#include <hip/hip_runtime.h>
#include <hip/hip_bf16.h>

#define TT 512
#define NB 1024

typedef float f32x4 __attribute__((ext_vector_type(4)));
typedef __bf16 bf16x8 __attribute__((ext_vector_type(8)));

// ---- workspace layout (units: __bf16 elements) ----
// Each 256x256 matrix packed as [kt][nt][lane][j] B-fragments for
// v_mfma_f32_16x16x32_bf16: B[k = kt*32 + (lane>>4)*8 + j][n = nt*16 + (lane&15)]
#define OFF_WHP   0
#define OFF_WMH   65536
#define OFF_WPOST 131072
#define OFF_WR1   196608
#define OFF_WMX   262144
#define OFF_WCP   327680   // 64x256 -> 16384 elems
#define WS_ELEMS  344064

__global__ __launch_bounds__(256) void pack_weights(
    const float* __restrict__ Whp, const float* __restrict__ Wm,
    const float* __restrict__ Wcp, const float* __restrict__ Whpost,
    const float* __restrict__ Wr1, __bf16* __restrict__ wsp) {
  int id = blockIdx.x * 256 + threadIdx.x;
  if (id >= WS_ELEMS) return;
  int rel; const float* src;
  if (id < OFF_WMH)        { rel = id - OFF_WHP;   src = Whp; }
  else if (id < OFF_WPOST) { rel = id - OFF_WMH;   src = Wm; }          // Wm rows 0..255
  else if (id < OFF_WR1)   { rel = id - OFF_WPOST; src = Whpost; }
  else if (id < OFF_WMX)   { rel = id - OFF_WR1;   src = Wr1; }
  else if (id < OFF_WCP)   { rel = id - OFF_WMX;   src = Wm + 256*256; } // Wm rows 256..511
  else                     { rel = id - OFF_WCP;   src = Wcp; }
  int j    = rel & 7;
  int lane = (rel >> 3) & 63;
  int nt   = (rel >> 9) & 15;
  int kt   = rel >> 13;
  int k = kt*32 + ((lane >> 4) << 3) + j;
  int n = nt*16 + (lane & 15);
  wsp[id] = (__bf16)src[k*256 + n];
}

__device__ __forceinline__ float tanh_fast(float x) {
  float t = __expf(2.0f * x);
  return 1.0f - __fdividef(2.0f, t + 1.0f);
}

// ---- 8-wave config: wave wv owns ntiles {2wv, 2wv+1} (cols [32wv, 32wv+32)) ----
// A-fragments from LDS tile in fragment order:
//   tile[(kt*64 + lane)*8 + j]  <->  A[m = lane&15][k = kt*32 + (lane>>4)*8 + j]

template<int KT>
__device__ __forceinline__ void gemm_stream2(
    f32x4 acc[2], const __bf16* __restrict__ Wp,
    const __bf16* atile, int wv, int lane) {
  constexpr int PF = (KT < 4) ? KT : 4;
  bf16x8 bbuf[PF][2];
  #pragma unroll
  for (int p = 0; p < PF; ++p)
    #pragma unroll
    for (int a = 0; a < 2; ++a)
      bbuf[p][a] = *(const bf16x8*)(Wp + ((p*16 + wv*2 + a)*64 + lane)*8);
  #pragma unroll
  for (int kt = 0; kt < KT; ++kt) {
    bf16x8 af = *(const bf16x8*)(atile + (kt*64 + lane)*8);
    #pragma unroll
    for (int a = 0; a < 2; ++a)
      acc[a] = __builtin_amdgcn_mfma_f32_16x16x32_bf16(af, bbuf[kt % PF][a], acc[a], 0, 0, 0);
    if (kt + PF < KT) {
      #pragma unroll
      for (int a = 0; a < 2; ++a)
        bbuf[kt % PF][a] = *(const bf16x8*)(Wp + (((kt+PF)*16 + wv*2 + a)*64 + lane)*8);
    }
  }
}

// Two B matrices sharing one A-tile read stream (hp + r1 both consume h).
__device__ __forceinline__ void gemm_dual8(
    f32x4 acc1[2], f32x4 acc2[2],
    const __bf16* __restrict__ W1, const __bf16* __restrict__ W2,
    const __bf16* atile, int wv, int lane) {
  constexpr int PF = 4;
  bf16x8 b1[PF][2], b2[PF][2];
  #pragma unroll
  for (int p = 0; p < PF; ++p)
    #pragma unroll
    for (int a = 0; a < 2; ++a) {
      b1[p][a] = *(const bf16x8*)(W1 + ((p*16 + wv*2 + a)*64 + lane)*8);
      b2[p][a] = *(const bf16x8*)(W2 + ((p*16 + wv*2 + a)*64 + lane)*8);
    }
  #pragma unroll
  for (int kt = 0; kt < 8; ++kt) {
    bf16x8 af = *(const bf16x8*)(atile + (kt*64 + lane)*8);
    #pragma unroll
    for (int a = 0; a < 2; ++a) {
      acc1[a] = __builtin_amdgcn_mfma_f32_16x16x32_bf16(af, b1[kt % PF][a], acc1[a], 0, 0, 0);
      acc2[a] = __builtin_amdgcn_mfma_f32_16x16x32_bf16(af, b2[kt % PF][a], acc2[a], 0, 0, 0);
    }
    if (kt + PF < 8) {
      #pragma unroll
      for (int a = 0; a < 2; ++a) {
        b1[kt % PF][a] = *(const bf16x8*)(W1 + (((kt+PF)*16 + wv*2 + a)*64 + lane)*8);
        b2[kt % PF][a] = *(const bf16x8*)(W2 + (((kt+PF)*16 + wv*2 + a)*64 + lane)*8);
      }
    }
  }
}

// C-layout (col = strip + lane&15, row = (lane>>4)*4 + r) -> tanh -> bf16 ->
// LDS tile in A-fragment order for the next GEMM.
__device__ __forceinline__ void tanh_store2(__bf16* tile, const f32x4 acc[2],
                                            int wv, int lane) {
  int l15 = lane & 15, lq = lane >> 4;
  #pragma unroll
  for (int a = 0; a < 2; ++a) {
    int col = wv*32 + a*16 + l15;
    int kt  = col >> 5;
    int lp  = 16 * ((col & 31) >> 3);
    int j   = col & 7;
    #pragma unroll
    for (int r = 0; r < 4; ++r) {
      int row = lq*4 + r;
      tile[(kt*64 + lp + row)*8 + j] = (__bf16)tanh_fast(acc[a][r]);
    }
  }
}

__device__ __forceinline__ void init_acc2(f32x4 acc[2], const float* b,
                                          int wv, int l15) {
  #pragma unroll
  for (int a = 0; a < 2; ++a) {
    float v = b[wv*32 + a*16 + l15];
    acc[a] = (f32x4){v, v, v, v};
  }
}

// relu(ar) @ Wr2 + br2 for this wave's 32 cols, reduce, atomic-accumulate.
__device__ __forceinline__ void regress_store(const f32x4 ar[2], const float* lb,
                                              float* out, int t, int n0,
                                              int wv, int lane, float br2v) {
  int l15 = lane & 15, lq = lane >> 4;
  float s[4] = {0.f, 0.f, 0.f, 0.f};
  #pragma unroll
  for (int a = 0; a < 2; ++a) {
    float w2 = lb[5*256 + wv*32 + a*16 + l15];
    #pragma unroll
    for (int r = 0; r < 4; ++r)
      s[r] += fmaxf(ar[a][r], 0.0f) * w2;
  }
  #pragma unroll
  for (int m = 1; m < 16; m <<= 1) {
    #pragma unroll
    for (int r = 0; r < 4; ++r) s[r] += __shfl_xor(s[r], m, 64);
  }
  if (l15 == 0) {
    #pragma unroll
    for (int r = 0; r < 4; ++r)
      atomicAdd(out + (size_t)t*NB + n0 + lq*4 + r, s[r] + br2v);
  }
}

__global__ __launch_bounds__(512, 2) void rnn_seq(
    const float* __restrict__ x, const __bf16* __restrict__ wsp,
    const float* __restrict__ bhp, const float* __restrict__ bcp,
    const float* __restrict__ bm, const float* __restrict__ bhpost,
    const float* __restrict__ br1, const float* __restrict__ Wr2,
    const float* __restrict__ br2, float* __restrict__ out) {
  // tiles: 0 = h (persistent), 1 = tanh(hp), 2 = tanh(cp), 3 = tanh(u)
  __shared__ __bf16 tiles[4][4096];
  __shared__ float  lb[6*256];   // bhp, bcp, bm, bhpost, br1, Wr2

  const int tid  = threadIdx.x;
  const int wv   = tid >> 6;     // 0..7
  const int lane = tid & 63;
  const int l15  = lane & 15, lq = lane >> 4;
  const int n0   = blockIdx.x * 16;

  if (tid < 256) {
    lb[0*256 + tid] = bhp[tid];
    lb[1*256 + tid] = bcp[tid];
    lb[2*256 + tid] = bm[tid];
    lb[3*256 + tid] = bhpost[tid];
    lb[4*256 + tid] = br1[tid];
    lb[5*256 + tid] = Wr2[tid];
  }
  for (int i = tid; i < 4096; i += 512) tiles[0][i] = (__bf16)0.0f;  // h0 = 0
  const float br2v = br2[0] * 0.125f;   // each of 8 waves contributes br2/8
  __syncthreads();

  for (int t = 0; t < TT; ++t) {
    // x A-fragments (K=64 -> 2 ktiles), fp32 -> bf16 in regs
    const float* xp = x + ((size_t)t*NB + n0 + l15)*64 + lq*8;
    f32x4 xa0 = *(const f32x4*)(xp);
    f32x4 xa1 = *(const f32x4*)(xp + 4);
    f32x4 xb0 = *(const f32x4*)(xp + 32);
    f32x4 xb1 = *(const f32x4*)(xp + 36);
    bf16x8 xf0, xf1;
    #pragma unroll
    for (int j = 0; j < 4; ++j) {
      xf0[j] = (__bf16)xa0[j]; xf0[4+j] = (__bf16)xa1[j];
      xf1[j] = (__bf16)xb0[j]; xf1[4+j] = (__bf16)xb1[j];
    }

    // ---- section A: hp = h@Whp + bhp ; cp = x@Wcp + bcp ;
    //                 regressor for step t-1 (shares A-reads of h with hp) ----
    f32x4 ah[2], ac[2], ar[2];
    init_acc2(ah, lb + 0*256, wv, l15);
    init_acc2(ac, lb + 1*256, wv, l15);
    init_acc2(ar, lb + 4*256, wv, l15);
    {
      bf16x8 bb[2][2];
      #pragma unroll
      for (int p = 0; p < 2; ++p)
        #pragma unroll
        for (int a = 0; a < 2; ++a)
          bb[p][a] = *(const bf16x8*)(wsp + OFF_WCP + ((p*16 + wv*2 + a)*64 + lane)*8);
      #pragma unroll
      for (int a = 0; a < 2; ++a) {
        ac[a] = __builtin_amdgcn_mfma_f32_16x16x32_bf16(xf0, bb[0][a], ac[a], 0, 0, 0);
        ac[a] = __builtin_amdgcn_mfma_f32_16x16x32_bf16(xf1, bb[1][a], ac[a], 0, 0, 0);
      }
    }
    gemm_dual8(ah, ar, wsp + OFF_WHP, wsp + OFF_WR1, tiles[0], wv, lane);
    tanh_store2(tiles[1], ah, wv, lane);
    tanh_store2(tiles[2], ac, wv, lane);
    if (t > 0)
      regress_store(ar, lb, out, t - 1, n0, wv, lane, br2v);
    __syncthreads();

    // ---- section B: u = tanh(hp)@Wm_h + tanh(cp)@Wm_x + bm ----
    f32x4 au[2], av[2];
    init_acc2(au, lb + 2*256, wv, l15);
    av[0] = (f32x4){0.f, 0.f, 0.f, 0.f};
    av[1] = (f32x4){0.f, 0.f, 0.f, 0.f};
    gemm_stream2<8>(au, wsp + OFF_WMH, tiles[1], wv, lane);
    gemm_stream2<8>(av, wsp + OFF_WMX, tiles[2], wv, lane);
    au[0] += av[0]; au[1] += av[1];
    tanh_store2(tiles[3], au, wv, lane);
    __syncthreads();

    // ---- section C: h_new = tanh(tanh(u)@Whpost + bhpost) ----
    f32x4 ap[2];
    init_acc2(ap, lb + 3*256, wv, l15);
    gemm_stream2<8>(ap, wsp + OFF_WPOST, tiles[3], wv, lane);
    tanh_store2(tiles[0], ap, wv, lane);
    __syncthreads();
  }

  // ---- tail: regressor for the final step ----
  f32x4 ar[2];
  init_acc2(ar, lb + 4*256, wv, l15);
  gemm_stream2<8>(ar, wsp + OFF_WR1, tiles[0], wv, lane);
  regress_store(ar, lb, out, TT - 1, n0, wv, lane, br2v);
}

extern "C" void kernel_launch(void* const* d_in, const int* in_sizes, int n_in,
                              void* d_out, int out_size, void* d_ws, size_t ws_size,
                              hipStream_t stream) {
  const float* x      = (const float*)d_in[0];
  const float* Whp    = (const float*)d_in[1];
  const float* bhp    = (const float*)d_in[2];
  const float* Wcp    = (const float*)d_in[3];
  const float* bcp    = (const float*)d_in[4];
  const float* Wm     = (const float*)d_in[5];
  const float* bm     = (const float*)d_in[6];
  const float* Whpost = (const float*)d_in[7];
  const float* bhpost = (const float*)d_in[8];
  const float* Wr1    = (const float*)d_in[9];
  const float* br1    = (const float*)d_in[10];
  const float* Wr2    = (const float*)d_in[11];
  const float* br2    = (const float*)d_in[12];
  __bf16* wsp = (__bf16*)d_ws;
  float*  out = (float*)d_out;

  if (ws_size < (size_t)WS_ELEMS * sizeof(__bf16)) return;

  hipMemsetAsync(out, 0, (size_t)out_size * sizeof(float), stream);
  pack_weights<<<WS_ELEMS / 256, 256, 0, stream>>>(Whp, Wm, Wcp, Whpost, Wr1, wsp);
  rnn_seq<<<64, 512, 0, stream>>>(x, wsp, bhp, bcp, bm, bhpost, br1, Wr2, br2, out);
}